// Round 1
// baseline (280.754 us; speedup 1.0000x reference)
//
#include <hip/hip_runtime.h>

// B=8, S=256, C=256, V=64 — fp32 inputs/outputs, fp16 MFMA internally.
// out[b,s,z,k] = tanh( BIL + r[b,z,k] + t[b,s,k] )
//   W_eff[i,j,k] = W[i,j,k] + (i==j)*linmul_w[k,j]
//   tmp[(b,s)][k][j] = sum_i ctx[b,s,i] * W_eff[i,j,k]          (GEMM1, n'=k*256+j)
//   BIL[b,s,z,k]     = sum_j ctx[b,z,j] * tmp[(b,s)][k][j]      (GEMM2)
//   r[b,z,k] = ctx[b,z,:]·(lin1_w[k,:]+lindiff_w[k,:]) + lin1_b[k]
//   t[b,s,k] = ctx[b,s,:]·(lin2_w[k,:]-lindiff_w[k,:]) + lin2_b[k]
//              + bias[k] + linmul_b[k] + lindiff_b[k]
//
// R1 change: operand-swapped MFMA in both GEMMs so each lane's 4 acc values are
// consecutive along the fast store dim; gemm1 epilogue goes through a per-wave
// LDS transpose tile -> half8 (128B-coalesced) tmp stores; gemm2 epilogue uses
// float4 rb/Ts loads and float4 out stores. Math/order unchanged.

typedef __attribute__((ext_vector_type(8))) _Float16 half8;
typedef __attribute__((ext_vector_type(4))) _Float16 half4v;
typedef __attribute__((ext_vector_type(4))) float f32x4;

__device__ __forceinline__ void async16(const void* g, void* l) {
  __builtin_amdgcn_global_load_lds(
      (__attribute__((address_space(1))) void*)g,
      (__attribute__((address_space(3))) void*)l, 16, 0, 0);
}

// ---- prep 0: ctx fp32 -> fp16 ----
__global__ __launch_bounds__(256) void prep_ctx(const float* __restrict__ ctx,
                                                _Float16* __restrict__ ch) {
  int idx = (blockIdx.x * 256 + threadIdx.x) * 4;
  float4 v = *(const float4*)(ctx + idx);
  half4v o;
  o[0] = (_Float16)v.x; o[1] = (_Float16)v.y;
  o[2] = (_Float16)v.z; o[3] = (_Float16)v.w;
  *(half4v*)(ch + idx) = o;
}

// ---- prep 1: wt[n'=(k*256+j)][i] = fp16( W[i][j][k] + (i==j)*lmw[k*256+j] ) ----
// one block per j
__global__ __launch_bounds__(256) void prep_wt(const float* __restrict__ W,
                                               const float* __restrict__ lmw,
                                               _Float16* __restrict__ wt) {
  __shared__ _Float16 T[256 * 68];  // [i][k], pad 64->68
  const int t = threadIdx.x;
  const int j = blockIdx.x;
#pragma unroll
  for (int p = 0; p < 16; ++p) {
    int i = p * 16 + (t >> 4);
    int c = t & 15;  // float4 chunk along k
    float4 v = *(const float4*)&W[(size_t)i * 16384 + j * 64 + c * 4];
    if (i == j) {
      v.x += lmw[(c * 4 + 0) * 256 + j];
      v.y += lmw[(c * 4 + 1) * 256 + j];
      v.z += lmw[(c * 4 + 2) * 256 + j];
      v.w += lmw[(c * 4 + 3) * 256 + j];
    }
    half4v o;
    o[0] = (_Float16)v.x; o[1] = (_Float16)v.y;
    o[2] = (_Float16)v.z; o[3] = (_Float16)v.w;
    *(half4v*)&T[i * 68 + c * 4] = o;
  }
  __syncthreads();
  const int k = t >> 2, i0 = (t & 3) * 64;
  _Float16* dst = wt + ((size_t)(k * 256 + j)) * 256 + i0;
#pragma unroll
  for (int u = 0; u < 64; u += 8) {
    half8 o;
#pragma unroll
    for (int e = 0; e < 8; ++e) o[e] = T[(i0 + u + e) * 68 + k];
    *(half8*)(dst + u) = o;
  }
}

// ---- prep 2: r[row][k], t[row][k] fp32 (row = b*256+s) ----
__global__ __launch_bounds__(256) void prep_rt(
    const float* __restrict__ ctx, const float* __restrict__ bias,
    const float* __restrict__ l1w, const float* __restrict__ l1b,
    const float* __restrict__ l2w, const float* __restrict__ l2b,
    const float* __restrict__ lmb, const float* __restrict__ ldw,
    const float* __restrict__ ldb, float* __restrict__ rbuf,
    float* __restrict__ tbuf) {
  __shared__ float Cs[4 * 256];
  const int t = threadIdx.x;
  const int row0 = blockIdx.x * 4;
  ((float4*)Cs)[t] = ((const float4*)(ctx + (size_t)row0 * 256))[t];
  __syncthreads();
  const int k = t & 63, lr = t >> 6;
  const float* l1r = l1w + k * 256;
  const float* l2r = l2w + k * 256;
  const float* ldr = ldw + k * 256;
  float a1 = 0.f, a2 = 0.f;
  for (int c = 0; c < 256; c += 4) {
    float4 w1 = *(const float4*)(l1r + c);
    float4 w2 = *(const float4*)(l2r + c);
    float4 wd = *(const float4*)(ldr + c);
    float4 cv = *(const float4*)(&Cs[lr * 256 + c]);
    a1 += cv.x * (w1.x + wd.x) + cv.y * (w1.y + wd.y) +
          cv.z * (w1.z + wd.z) + cv.w * (w1.w + wd.w);
    a2 += cv.x * (w2.x - wd.x) + cv.y * (w2.y - wd.y) +
          cv.z * (w2.z - wd.z) + cv.w * (w2.w - wd.w);
  }
  int row = row0 + lr;
  rbuf[row * 64 + k] = a1 + l1b[k];
  tbuf[row * 64 + k] = a2 + l2b[k] + bias[k] + lmb[k] + ldb[k];
}

// ---- GEMM1: tmp[m][n'] = ctx_h[m][:] . wt[n'][:]  (M=2048, N=16384, K=256) ----
// Swapped MFMA: acc[ni][mi] has row-dim = n (wt rows), col-dim = m (ctx rows),
// so each lane holds 4 consecutive n for a fixed m -> LDS transpose -> half8 stores.
__global__ __launch_bounds__(256) void gemm1(const _Float16* __restrict__ ch,
                                             const _Float16* __restrict__ wt,
                                             _Float16* __restrict__ tmp) {
  // 36 KB pool: [0,8KB) As, [8KB,16KB) Bs during K-loop; 4x (64x72) fp16
  // per-wave transpose tiles in the epilogue (after final barrier).
  __shared__ _Float16 pool[4 * 64 * 72];
  _Float16* As = pool;           // 128*32
  _Float16* Bs = pool + 4096;    // 128*32
  const int t = threadIdx.x;
  const int lane = t & 63, wave = t >> 6;
  const int m0 = blockIdx.y * 128, n0 = blockIdx.x * 128;
  const int wm = (wave & 1) * 64, wn = (wave >> 1) * 64;
  const int r = lane & 15, q = lane >> 4;
  f32x4 acc[4][4] = {};  // acc[ni][mi]
  const _Float16* gA = ch + (size_t)(m0 + (t >> 2)) * 256 + (t & 3) * 8;
  const _Float16* gB = wt + (size_t)(n0 + (t >> 2)) * 256 + (t & 3) * 8;
  for (int k0 = 0; k0 < 256; k0 += 32) {
    async16(gA + k0, &As[t * 8]);
    async16(gA + 64 * 256 + k0, &As[2048 + t * 8]);
    async16(gB + k0, &Bs[t * 8]);
    async16(gB + 64 * 256 + k0, &Bs[2048 + t * 8]);
    __syncthreads();
    half8 a[4], b[4];
#pragma unroll
    for (int mi = 0; mi < 4; ++mi)
      a[mi] = *(const half8*)&As[(wm + mi * 16 + r) * 32 + q * 8];
#pragma unroll
    for (int ni = 0; ni < 4; ++ni)
      b[ni] = *(const half8*)&Bs[(wn + ni * 16 + r) * 32 + q * 8];
#pragma unroll
    for (int ni = 0; ni < 4; ++ni)
#pragma unroll
      for (int mi = 0; mi < 4; ++mi)
        acc[ni][mi] = __builtin_amdgcn_mfma_f32_16x16x32_f16(b[ni], a[mi],
                                                             acc[ni][mi], 0, 0, 0);
    __syncthreads();
  }
  // Epilogue: per-wave 64x72 LDS tile [m][n], then 128B-coalesced half8 stores.
  _Float16* Sw = pool + wave * 4608;
#pragma unroll
  for (int ni = 0; ni < 4; ++ni)
#pragma unroll
    for (int mi = 0; mi < 4; ++mi) {
      half4v h;
#pragma unroll
      for (int e = 0; e < 4; ++e) h[e] = (_Float16)acc[ni][mi][e];
      *(half4v*)&Sw[(mi * 16 + r) * 72 + ni * 16 + q * 4] = h;
    }
  __syncthreads();
  const int g2 = lane >> 3, c2 = lane & 7;
  _Float16* dst = tmp + (size_t)(m0 + wm) * 16384 + (n0 + wn);
#pragma unroll
  for (int u = 0; u < 8; ++u) {
    int row = u * 8 + g2;
    half8 vv = *(const half8*)&Sw[row * 72 + c2 * 8];
    *(half8*)(dst + (size_t)row * 16384 + c2 * 8) = vv;
  }
}

// ---- GEMM2 + epilogue: block per (b,s); out[z][k] = tanh(ctx_b @ tmp_bs^T + r + t) ----
// Swapped MFMA: acc[ki][zi] has row-dim = k (tmp rows), col-dim = z (ctx rows),
// so each lane holds 4 consecutive k for a fixed z -> float4 loads/stores.
__global__ __launch_bounds__(256) void gemm2(const _Float16* __restrict__ ch,
                                             const _Float16* __restrict__ tmp,
                                             const float* __restrict__ rbuf,
                                             const float* __restrict__ tbuf,
                                             float* __restrict__ out) {
  __shared__ _Float16 As[256 * 32];  // ctx_b [z][j-chunk]
  __shared__ _Float16 Bs[64 * 32];   // tmp_bs [k][j-chunk] (already transposed!)
  __shared__ float Ts[64];
  const int t = threadIdx.x;
  const int lane = t & 63, wave = t >> 6;
  const int bs = blockIdx.x;
  const int b = bs >> 8;
  const int r = lane & 15, q = lane >> 4;
  const _Float16* ctxb = ch + (size_t)b * 65536;
  const _Float16* tm = tmp + (size_t)bs * 16384;
  if (t < 64) Ts[t] = tbuf[bs * 64 + t];
  f32x4 acc[4][4] = {};  // acc[ki][zi]
  for (int j0 = 0; j0 < 256; j0 += 32) {
#pragma unroll
    for (int p = 0; p < 4; ++p)
      async16(ctxb + (size_t)(p * 64 + (t >> 2)) * 256 + j0 + (t & 3) * 8,
              &As[p * 2048 + t * 8]);
    async16(tm + (size_t)(t >> 2) * 256 + j0 + (t & 3) * 8, &Bs[t * 8]);
    __syncthreads();
    half8 a[4], bf[4];
#pragma unroll
    for (int zi = 0; zi < 4; ++zi)
      a[zi] = *(const half8*)&As[(wave * 64 + zi * 16 + r) * 32 + q * 8];
#pragma unroll
    for (int ki = 0; ki < 4; ++ki)
      bf[ki] = *(const half8*)&Bs[(ki * 16 + r) * 32 + q * 8];
#pragma unroll
    for (int ki = 0; ki < 4; ++ki)
#pragma unroll
      for (int zi = 0; zi < 4; ++zi)
        acc[ki][zi] = __builtin_amdgcn_mfma_f32_16x16x32_f16(bf[ki], a[zi],
                                                             acc[ki][zi], 0, 0, 0);
    __syncthreads();
  }
  const float* rb = rbuf + (size_t)b * 16384;
#pragma unroll
  for (int ki = 0; ki < 4; ++ki)
#pragma unroll
    for (int zi = 0; zi < 4; ++zi) {
      int z = wave * 64 + zi * 16 + r;
      int k = ki * 16 + q * 4;
      f32x4 rv = *(const f32x4*)&rb[z * 64 + k];
      f32x4 tv = *(const f32x4*)&Ts[k];
      f32x4 o;
#pragma unroll
      for (int e = 0; e < 4; ++e) {
        float x = acc[ki][zi][e] + rv[e] + tv[e];
        float ax = fabsf(x);
        float ev = __expf(-2.0f * ax);
        float y = (1.0f - ev) / (1.0f + ev);
        o[e] = copysignf(y, x);
      }
      *(f32x4*)&out[((size_t)bs * 256 + z) * 64 + k] = o;
    }
}

extern "C" void kernel_launch(void* const* d_in, const int* in_sizes, int n_in,
                              void* d_out, int out_size, void* d_ws, size_t ws_size,
                              hipStream_t stream) {
  const float* ctx  = (const float*)d_in[0];
  const float* W    = (const float*)d_in[1];
  const float* bias = (const float*)d_in[2];
  const float* l1w  = (const float*)d_in[3];
  const float* l1b  = (const float*)d_in[4];
  const float* l2w  = (const float*)d_in[5];
  const float* l2b  = (const float*)d_in[6];
  const float* lmw  = (const float*)d_in[7];
  const float* lmb  = (const float*)d_in[8];
  const float* ldw  = (const float*)d_in[9];
  const float* ldb  = (const float*)d_in[10];
  float* out = (float*)d_out;

  char* ws = (char*)d_ws;
  _Float16* ch  = (_Float16*)ws;                               // 1 MiB ctx fp16
  _Float16* wt  = (_Float16*)(ws + (1u << 20));                // 8 MiB W_eff^T fp16
  _Float16* tmp = (_Float16*)(ws + (9u << 20));                // 64 MiB tmp fp16
  float* rbuf = (float*)(ws + (73u << 20));                    // 512 KiB
  float* tbuf = rbuf + 2048 * 64;                              // 512 KiB

  prep_ctx<<<512, 256, 0, stream>>>(ctx, ch);
  prep_wt<<<256, 256, 0, stream>>>(W, lmw, wt);
  prep_rt<<<512, 256, 0, stream>>>(ctx, bias, l1w, l1b, l2w, l2b, lmb, ldw, ldb,
                                   rbuf, tbuf);
  gemm1<<<dim3(128, 16), 256, 0, stream>>>(ch, wt, tmp);
  gemm2<<<2048, 256, 0, stream>>>(ch, tmp, rbuf, tbuf, out);
}

// Round 2
// 247.886 us; speedup vs baseline: 1.1326x; 1.1326x over previous
//
#include <hip/hip_runtime.h>

// B=8, S=256, C=256, V=64 — fp32 inputs/outputs, fp16 MFMA internally.
// out[b,s,z,k] = tanh( BIL + r[b,z,k] + t[b,s,k] )
//   W_eff[i,j,k] = W[i,j,k] + (i==j)*linmul_w[k,j]
//   tmp[(b,s)][k][j] = sum_i ctx[b,s,i] * W_eff[i,j,k]          (GEMM1, n'=k*256+j)
//   BIL[b,s,z,k]     = sum_j ctx[b,z,j] * tmp[(b,s)][k][j]      (GEMM2)
//   r[b,z,k] = ctx[b,z,:]·(lin1_w[k,:]+lindiff_w[k,:]) + lin1_b[k]
//   t[b,s,k] = ctx[b,s,:]·(lin2_w[k,:]-lindiff_w[k,:]) + lin2_b[k]
//              + bias[k] + linmul_b[k] + lindiff_b[k]
//
// R2: (1) T2 XOR-swizzle on all fragment LDS reads (chunk ^= row&7), fed by
// pre-swizzled global_load_lds sources (linear LDS dest) — kills the 8-way
// bank conflict on every ds_read_b128; (2) BK=64 K-steps (half the barrier
// drains); (3) bijective XCD-chunked block swizzle on both GEMMs for L2
// locality; (4) prep_rt does 16 rows/block (4x less weight re-read traffic).
// Math order unchanged.

typedef __attribute__((ext_vector_type(8))) _Float16 half8;
typedef __attribute__((ext_vector_type(4))) _Float16 half4v;
typedef __attribute__((ext_vector_type(4))) float f32x4;

__device__ __forceinline__ void async16(const void* g, void* l) {
  __builtin_amdgcn_global_load_lds(
      (__attribute__((address_space(1))) void*)g,
      (__attribute__((address_space(3))) void*)l, 16, 0, 0);
}

// ---- prep 0: ctx fp32 -> fp16 ----
__global__ __launch_bounds__(256) void prep_ctx(const float* __restrict__ ctx,
                                                _Float16* __restrict__ ch) {
  int idx = (blockIdx.x * 256 + threadIdx.x) * 4;
  float4 v = *(const float4*)(ctx + idx);
  half4v o;
  o[0] = (_Float16)v.x; o[1] = (_Float16)v.y;
  o[2] = (_Float16)v.z; o[3] = (_Float16)v.w;
  *(half4v*)(ch + idx) = o;
}

// ---- prep 1: wt[n'=(k*256+j)][i] = fp16( W[i][j][k] + (i==j)*lmw[k*256+j] ) ----
__global__ __launch_bounds__(256) void prep_wt(const float* __restrict__ W,
                                               const float* __restrict__ lmw,
                                               _Float16* __restrict__ wt) {
  __shared__ _Float16 T[256 * 68];  // [i][k], pad 64->68
  const int t = threadIdx.x;
  const int j = blockIdx.x;
#pragma unroll
  for (int p = 0; p < 16; ++p) {
    int i = p * 16 + (t >> 4);
    int c = t & 15;  // float4 chunk along k
    float4 v = *(const float4*)&W[(size_t)i * 16384 + j * 64 + c * 4];
    if (i == j) {
      v.x += lmw[(c * 4 + 0) * 256 + j];
      v.y += lmw[(c * 4 + 1) * 256 + j];
      v.z += lmw[(c * 4 + 2) * 256 + j];
      v.w += lmw[(c * 4 + 3) * 256 + j];
    }
    half4v o;
    o[0] = (_Float16)v.x; o[1] = (_Float16)v.y;
    o[2] = (_Float16)v.z; o[3] = (_Float16)v.w;
    *(half4v*)&T[i * 68 + c * 4] = o;
  }
  __syncthreads();
  const int k = t >> 2, i0 = (t & 3) * 64;
  _Float16* dst = wt + ((size_t)(k * 256 + j)) * 256 + i0;
#pragma unroll
  for (int u = 0; u < 64; u += 8) {
    half8 o;
#pragma unroll
    for (int e = 0; e < 8; ++e) o[e] = T[(i0 + u + e) * 68 + k];
    *(half8*)(dst + u) = o;
  }
}

// ---- prep 2: r[row][k], t[row][k] fp32 (row = b*256+s); 16 rows/block ----
__global__ __launch_bounds__(256) void prep_rt(
    const float* __restrict__ ctx, const float* __restrict__ bias,
    const float* __restrict__ l1w, const float* __restrict__ l1b,
    const float* __restrict__ l2w, const float* __restrict__ l2b,
    const float* __restrict__ lmb, const float* __restrict__ ldw,
    const float* __restrict__ ldb, float* __restrict__ rbuf,
    float* __restrict__ tbuf) {
  __shared__ float Cs[16 * 256];
  const int t = threadIdx.x;
  const int row0 = blockIdx.x * 16;
#pragma unroll
  for (int p = 0; p < 4; ++p)
    ((float4*)Cs)[p * 256 + t] =
        ((const float4*)(ctx + (size_t)row0 * 256))[p * 256 + t];
  __syncthreads();
  const int k = t & 63, lr = t >> 6;  // wave lr handles rows lr*4 .. lr*4+3
  const float* l1r = l1w + k * 256;
  const float* l2r = l2w + k * 256;
  const float* ldr = ldw + k * 256;
  float a1[4] = {0.f, 0.f, 0.f, 0.f};
  float a2[4] = {0.f, 0.f, 0.f, 0.f};
  for (int c = 0; c < 256; c += 4) {
    float4 w1 = *(const float4*)(l1r + c);
    float4 w2 = *(const float4*)(l2r + c);
    float4 wd = *(const float4*)(ldr + c);
    float4 s1, s2;
    s1.x = w1.x + wd.x; s1.y = w1.y + wd.y; s1.z = w1.z + wd.z; s1.w = w1.w + wd.w;
    s2.x = w2.x - wd.x; s2.y = w2.y - wd.y; s2.z = w2.z - wd.z; s2.w = w2.w - wd.w;
#pragma unroll
    for (int u = 0; u < 4; ++u) {
      float4 cv = *(const float4*)(&Cs[(lr * 4 + u) * 256 + c]);
      a1[u] += cv.x * s1.x + cv.y * s1.y + cv.z * s1.z + cv.w * s1.w;
      a2[u] += cv.x * s2.x + cv.y * s2.y + cv.z * s2.z + cv.w * s2.w;
    }
  }
  float tb = l2b[k] + bias[k] + lmb[k] + ldb[k];
  float rb = l1b[k];
#pragma unroll
  for (int u = 0; u < 4; ++u) {
    int row = row0 + lr * 4 + u;
    rbuf[row * 64 + k] = a1[u] + rb;
    tbuf[row * 64 + k] = a2[u] + tb;
  }
}

// ---- GEMM1: tmp[m][n'] = ctx_h[m][:] . wt[n'][:]  (M=2048, N=16384, K=256) ----
// BK=64, XOR-swizzled LDS (chunk ^= row&7), swapped MFMA (acc[ni][mi]),
// LDS-transpose epilogue -> half8 coalesced tmp stores.
__global__ __launch_bounds__(256) void gemm1(const _Float16* __restrict__ ch,
                                             const _Float16* __restrict__ wt,
                                             _Float16* __restrict__ tmp) {
  // 36 KB pool: [0,16KB) As, [16KB,32KB) Bs during K-loop (128 rows x 64 halfs
  // each); 4x (64x72) fp16 per-wave transpose tiles in the epilogue.
  __shared__ _Float16 pool[4 * 64 * 72];
  _Float16* As = pool;           // 128*64 halfs
  _Float16* Bs = pool + 8192;    // 128*64 halfs
  const int t = threadIdx.x;
  const int lane = t & 63, wave = t >> 6;
  // XCD-chunked bijective swizzle: nwg=2048, each XCD gets 16 consecutive
  // n-panels x all 16 m-panels (wt slice 1MB + ctx 1MB -> L2-resident).
  const int d = blockIdx.x + blockIdx.y * 128;
  const int w = (d & 7) * 256 + (d >> 3);
  const int m0 = (w & 15) * 128, n0 = (w >> 4) * 128;
  const int wm = (wave & 1) * 64, wn = (wave >> 1) * 64;
  const int r = lane & 15, q = lane >> 4;
  const int sr = r & 7;
  f32x4 acc[4][4] = {};  // acc[ni][mi]
  // Staging: thread t owns LDS (row = p*32 + (t>>3), chunk = t&7); global
  // source chunk is (t&7) ^ (row&7) so LDS[row][c] holds global chunk c^(row&7).
  const int cg = (t & 7) ^ ((t >> 3) & 7);
  const _Float16* gA = ch + (size_t)(m0 + (t >> 3)) * 256 + cg * 8;
  const _Float16* gB = wt + (size_t)(n0 + (t >> 3)) * 256 + cg * 8;
  for (int k0 = 0; k0 < 256; k0 += 64) {
#pragma unroll
    for (int p = 0; p < 4; ++p) {
      async16(gA + p * 32 * 256 + k0, &As[p * 2048 + t * 8]);
      async16(gB + p * 32 * 256 + k0, &Bs[p * 2048 + t * 8]);
    }
    __syncthreads();
#pragma unroll
    for (int kk = 0; kk < 2; ++kk) {
      const int ca = ((kk * 4 + q) ^ sr) * 8;  // swizzled 16B chunk offset
      half8 a[4], b[4];
#pragma unroll
      for (int mi = 0; mi < 4; ++mi)
        a[mi] = *(const half8*)&As[(wm + mi * 16 + r) * 64 + ca];
#pragma unroll
      for (int ni = 0; ni < 4; ++ni)
        b[ni] = *(const half8*)&Bs[(wn + ni * 16 + r) * 64 + ca];
#pragma unroll
      for (int ni = 0; ni < 4; ++ni)
#pragma unroll
        for (int mi = 0; mi < 4; ++mi)
          acc[ni][mi] = __builtin_amdgcn_mfma_f32_16x16x32_f16(
              b[ni], a[mi], acc[ni][mi], 0, 0, 0);
    }
    __syncthreads();
  }
  // Epilogue: per-wave 64x72 LDS tile [m][n], then 128B-coalesced half8 stores.
  _Float16* Sw = pool + wave * 4608;
#pragma unroll
  for (int ni = 0; ni < 4; ++ni)
#pragma unroll
    for (int mi = 0; mi < 4; ++mi) {
      half4v h;
#pragma unroll
      for (int e = 0; e < 4; ++e) h[e] = (_Float16)acc[ni][mi][e];
      *(half4v*)&Sw[(mi * 16 + r) * 72 + ni * 16 + q * 4] = h;
    }
  __syncthreads();
  const int g2 = lane >> 3, c2 = lane & 7;
  _Float16* dst = tmp + (size_t)(m0 + wm) * 16384 + (n0 + wn);
#pragma unroll
  for (int u = 0; u < 8; ++u) {
    int row = u * 8 + g2;
    half8 vv = *(const half8*)&Sw[row * 72 + c2 * 8];
    *(half8*)(dst + (size_t)row * 16384 + c2 * 8) = vv;
  }
}

// ---- GEMM2 + epilogue: block per (b,s); out[z][k] = tanh(ctx_b @ tmp_bs^T + r + t) ----
// BK=64, XOR-swizzled LDS, swapped MFMA (acc[ki][zi]) -> float4 epilogue.
__global__ __launch_bounds__(256) void gemm2(const _Float16* __restrict__ ch,
                                             const _Float16* __restrict__ tmp,
                                             const float* __restrict__ rbuf,
                                             const float* __restrict__ tbuf,
                                             float* __restrict__ out) {
  __shared__ _Float16 As[256 * 64];  // ctx_b [z][j-chunk]   32 KB
  __shared__ _Float16 Bs[64 * 64];   // tmp_bs [k][j-chunk]   8 KB
  __shared__ float Ts[64];
  const int t = threadIdx.x;
  const int lane = t & 63, wave = t >> 6;
  // XCD-chunked bijective swizzle: each XCD gets one batch b (256 blocks) ->
  // ctx_b (128 KB) and rbuf slice L2-resident.
  const int d = blockIdx.x;
  const int bs = (d & 7) * 256 + (d >> 3);
  const int b = bs >> 8;
  const int r = lane & 15, q = lane >> 4;
  const int sr = r & 7;
  const _Float16* ctxb = ch + (size_t)b * 65536;
  const _Float16* tm = tmp + (size_t)bs * 16384;
  if (t < 64) Ts[t] = tbuf[bs * 64 + t];
  f32x4 acc[4][4] = {};  // acc[ki][zi]
  const int cg = (t & 7) ^ ((t >> 3) & 7);
  const _Float16* gA = ctxb + (size_t)(t >> 3) * 256 + cg * 8;
  const _Float16* gB = tm + (size_t)(t >> 3) * 256 + cg * 8;
  for (int j0 = 0; j0 < 256; j0 += 64) {
#pragma unroll
    for (int p = 0; p < 8; ++p)
      async16(gA + p * 32 * 256 + j0, &As[p * 2048 + t * 8]);
#pragma unroll
    for (int p = 0; p < 2; ++p)
      async16(gB + p * 32 * 256 + j0, &Bs[p * 2048 + t * 8]);
    __syncthreads();
#pragma unroll
    for (int kk = 0; kk < 2; ++kk) {
      const int ca = ((kk * 4 + q) ^ sr) * 8;
      half8 a[4], bf[4];
#pragma unroll
      for (int zi = 0; zi < 4; ++zi)
        a[zi] = *(const half8*)&As[(wave * 64 + zi * 16 + r) * 64 + ca];
#pragma unroll
      for (int ki = 0; ki < 4; ++ki)
        bf[ki] = *(const half8*)&Bs[(ki * 16 + r) * 64 + ca];
#pragma unroll
      for (int ki = 0; ki < 4; ++ki)
#pragma unroll
        for (int zi = 0; zi < 4; ++zi)
          acc[ki][zi] = __builtin_amdgcn_mfma_f32_16x16x32_f16(
              bf[ki], a[zi], acc[ki][zi], 0, 0, 0);
    }
    __syncthreads();
  }
  const float* rb = rbuf + (size_t)b * 16384;
#pragma unroll
  for (int ki = 0; ki < 4; ++ki)
#pragma unroll
    for (int zi = 0; zi < 4; ++zi) {
      int z = wave * 64 + zi * 16 + r;
      int k = ki * 16 + q * 4;
      f32x4 rv = *(const f32x4*)&rb[z * 64 + k];
      f32x4 tv = *(const f32x4*)&Ts[k];
      f32x4 o;
#pragma unroll
      for (int e = 0; e < 4; ++e) {
        float x = acc[ki][zi][e] + rv[e] + tv[e];
        float ax = fabsf(x);
        float ev = __expf(-2.0f * ax);
        float y = (1.0f - ev) / (1.0f + ev);
        o[e] = copysignf(y, x);
      }
      *(f32x4*)&out[((size_t)bs * 256 + z) * 64 + k] = o;
    }
}

extern "C" void kernel_launch(void* const* d_in, const int* in_sizes, int n_in,
                              void* d_out, int out_size, void* d_ws, size_t ws_size,
                              hipStream_t stream) {
  const float* ctx  = (const float*)d_in[0];
  const float* W    = (const float*)d_in[1];
  const float* bias = (const float*)d_in[2];
  const float* l1w  = (const float*)d_in[3];
  const float* l1b  = (const float*)d_in[4];
  const float* l2w  = (const float*)d_in[5];
  const float* l2b  = (const float*)d_in[6];
  const float* lmw  = (const float*)d_in[7];
  const float* lmb  = (const float*)d_in[8];
  const float* ldw  = (const float*)d_in[9];
  const float* ldb  = (const float*)d_in[10];
  float* out = (float*)d_out;

  char* ws = (char*)d_ws;
  _Float16* ch  = (_Float16*)ws;                               // 1 MiB ctx fp16
  _Float16* wt  = (_Float16*)(ws + (1u << 20));                // 8 MiB W_eff^T fp16
  _Float16* tmp = (_Float16*)(ws + (9u << 20));                // 64 MiB tmp fp16
  float* rbuf = (float*)(ws + (73u << 20));                    // 512 KiB
  float* tbuf = rbuf + 2048 * 64;                              // 512 KiB

  prep_ctx<<<512, 256, 0, stream>>>(ctx, ch);
  prep_wt<<<256, 256, 0, stream>>>(W, lmw, wt);
  prep_rt<<<128, 256, 0, stream>>>(ctx, bias, l1w, l1b, l2w, l2b, lmb, ldw, ldb,
                                   rbuf, tbuf);
  gemm1<<<dim3(128, 16), 256, 0, stream>>>(ch, wt, tmp);
  gemm2<<<2048, 256, 0, stream>>>(ch, tmp, rbuf, tbuf, out);
}